// Round 1
// baseline (191.079 us; speedup 1.0000x reference)
//
#include <hip/hip_runtime.h>
#include <math.h>

#define Bsz 16
#define Gg  20000
#define Dd  256
#define Kk  2048

typedef short short8 __attribute__((ext_vector_type(8)));
typedef float f32x4  __attribute__((ext_vector_type(4)));

__device__ __forceinline__ unsigned short f2bf(float f) {
  unsigned u = __float_as_uint(f);
  unsigned r = u + 0x7FFFu + ((u >> 16) & 1u);   // round-to-nearest-even
  return (unsigned short)(r >> 16);
}

__device__ __forceinline__ float gelu_exact(float x) {
  return 0.5f * x * (1.0f + erff(x * 0.70710678118654752f));
}

// ---------------- kernel 1: w2 fp32 -> bf16 ----------------
__global__ __launch_bounds__(256) void k_w2bf(const float* __restrict__ w2,
                                              unsigned short* __restrict__ w2bf) {
  int i = (blockIdx.x * 256 + threadIdx.x) * 4;
  float4 v = *(const float4*)(w2 + i);
  ushort4 o;
  o.x = f2bf(v.x); o.y = f2bf(v.y); o.z = f2bf(v.z); o.w = f2bf(v.w);
  *(ushort4*)(w2bf + i) = o;
}

// ---------------- kernel 2: per-row exact top-K select + compact ----------------
// one block per batch row, 1024 threads
__global__ __launch_bounds__(1024) void k_select(
    const float* __restrict__ expr, const float* __restrict__ cls,
    int* __restrict__ comp_idx, float* __restrict__ expr_sel,
    float* __restrict__ out)
{
  const int b   = blockIdx.x;
  const int tid = threadIdx.x;
  const float* row = expr + (size_t)b * Gg;

  __shared__ unsigned hist[256];
  __shared__ unsigned sh_prefix, sh_kth;
  __shared__ unsigned s_scan[1024];

  if (tid == 0) { sh_prefix = 0u; sh_kth = Kk; }
  __syncthreads();

  // 4-pass radix select (descending) on float bits (all expr >= 0 -> uint order ok)
  for (int pass = 0; pass < 4; ++pass) {
    const int shift = 24 - pass * 8;
    if (tid < 256) hist[tid] = 0u;
    __syncthreads();
    unsigned prefix  = sh_prefix;
    unsigned mask_hi = (pass == 0) ? 0u : (0xFFFFFFFFu << (shift + 8));
    for (int i = tid; i < Gg; i += 1024) {
      unsigned bits = __float_as_uint(row[i]);
      if ((bits & mask_hi) == prefix)
        atomicAdd(&hist[(bits >> shift) & 0xFFu], 1u);
    }
    __syncthreads();
    if (tid == 0) {
      unsigned kth = sh_kth, cum = 0;
      int bin = 255;
      for (; bin >= 0; --bin) {
        unsigned c = hist[bin];
        if (cum + c >= kth) break;
        cum += c;
      }
      sh_kth    = kth - cum;
      sh_prefix = prefix | (((unsigned)bin) << shift);
    }
    __syncthreads();
  }

  const unsigned T       = sh_prefix;  // bit pattern of K-th largest value
  const unsigned need_eq = sh_kth;     // how many ==T to take (ascending index)

  // contiguous slice per thread (preserves ascending-index order)
  const int per = (Gg + 1023) / 1024;  // 20
  const int g0  = tid * per;
  const int g1  = (g0 + per < Gg) ? (g0 + per) : Gg;

  // stage 1: count equals per slice, scan -> eq rank base
  unsigned cnteq = 0;
  for (int g = g0; g < g1; ++g)
    if (__float_as_uint(row[g]) == T) ++cnteq;

  s_scan[tid] = cnteq; __syncthreads();
  for (int off = 1; off < 1024; off <<= 1) {
    unsigned add = (tid >= off) ? s_scan[tid - off] : 0u;
    __syncthreads();
    s_scan[tid] += add;
    __syncthreads();
  }
  const unsigned excl_eq = s_scan[tid] - cnteq;

  // stage 2: count kept (selected && value>0) per slice
  unsigned cnt = 0;
  {
    unsigned eqr = excl_eq;
    for (int g = g0; g < g1; ++g) {
      float v = row[g];
      unsigned bits = __float_as_uint(v);
      bool sel;
      if (bits > T)       sel = true;
      else if (bits == T) { sel = (eqr < need_eq); ++eqr; }
      else                sel = false;
      if (sel && v > 0.0f) ++cnt;
    }
  }
  __syncthreads();
  s_scan[tid] = cnt; __syncthreads();
  for (int off = 1; off < 1024; off <<= 1) {
    unsigned add = (tid >= off) ? s_scan[tid - off] : 0u;
    __syncthreads();
    s_scan[tid] += add;
    __syncthreads();
  }
  unsigned pos = s_scan[tid] - cnt;
  const unsigned n_b = s_scan[1023];

  // stage 3: write compacted indices + expr values
  {
    unsigned eqr = excl_eq;
    for (int g = g0; g < g1; ++g) {
      float v = row[g];
      unsigned bits = __float_as_uint(v);
      bool sel;
      if (bits > T)       sel = true;
      else if (bits == T) { sel = (eqr < need_eq); ++eqr; }
      else                sel = false;
      if (sel && v > 0.0f) {
        comp_idx[b * Kk + pos] = g;
        expr_sel[b * Kk + pos] = v;
        ++pos;
      }
    }
  }
  // padding slots
  for (int k = (int)n_b + tid; k < Kk; k += 1024) {
    comp_idx[b * Kk + k] = -1;
    expr_sel[b * Kk + k] = 0.0f;
  }

  // cls token + mask
  float* tok = out + (size_t)b * (Kk + 1) * Dd;
  if (tid < Dd) tok[tid] = cls[tid];
  float* maskp = out + (size_t)Bsz * (Kk + 1) * Dd + (size_t)b * (Kk + 1);
  for (int i = tid; i <= Kk; i += 1024)
    maskp[i] = (i == 0) ? 1.0f : (((unsigned)(i - 1) < n_b) ? 1.0f : 0.0f);
}

// ---------------- kernel 3: token compute (fused gelu + bf16 MFMA GEMM) ----------------
// block = 256 thr (4 waves), 64 token slots x 256 out dims; wave w owns e in [w*64, w*64+64)
__global__ __launch_bounds__(256) void k_tokens(
    const int* __restrict__ comp_idx, const float* __restrict__ expr_sel,
    const float* __restrict__ w1, const float* __restrict__ b1,
    const unsigned short* __restrict__ w2bf, const float* __restrict__ b2,
    const float* __restrict__ gene_emb, float* __restrict__ out)
{
  __shared__ unsigned short h_s[64 * 256];  // bf16, XOR-swizzled 16B chunks
  __shared__ int   s_g[64];
  __shared__ float s_x[64];

  const int tid   = threadIdx.x;
  const int slot0 = blockIdx.x * 64;

  if (tid < 64) {
    int slot = slot0 + tid;
    int gi = comp_idx[slot];
    s_g[tid] = gi;
    s_x[tid] = (gi >= 0) ? expr_sel[slot] : 0.0f;
  }
  __syncthreads();

  // phase 1: h[m][d] = gelu(x_m * w1[d] + b1[d]) -> bf16 in LDS
  // chunk id -> (token m = id>>5, 16B chunk c = id&31), swizzle c ^ (m&7)
  #pragma unroll
  for (int i = 0; i < 8; ++i) {
    int id = tid + 256 * i;
    int m  = id >> 5;
    int c  = id & 31;
    int d0 = c * 8;
    float x = s_x[m];
    float wv[8], bv[8];
    *(float4*)(&wv[0]) = *(const float4*)(w1 + d0);
    *(float4*)(&wv[4]) = *(const float4*)(w1 + d0 + 4);
    *(float4*)(&bv[0]) = *(const float4*)(b1 + d0);
    *(float4*)(&bv[4]) = *(const float4*)(b1 + d0 + 4);
    short8 p;
    #pragma unroll
    for (int j = 0; j < 8; ++j)
      p[j] = (short)f2bf(gelu_exact(x * wv[j] + bv[j]));
    int cs = c ^ (m & 7);
    *(short8*)(h_s + (m * 32 + cs) * 8) = p;
  }
  __syncthreads();

  // phase 2: GEMM. out[m][e] = sum_d h[m][d] * w2[e][d]
  const int wave = tid >> 6;
  const int lane = tid & 63;
  const int m16  = lane & 15;
  const int q    = lane >> 4;
  const int e_base = wave * 64;

  f32x4 acc[4][4];
  #pragma unroll
  for (int a = 0; a < 4; ++a)
    #pragma unroll
    for (int n = 0; n < 4; ++n)
      acc[a][n] = (f32x4){0.f, 0.f, 0.f, 0.f};

  #pragma unroll
  for (int kit = 0; kit < 8; ++kit) {
    short8 afrag[4];
    #pragma unroll
    for (int mt = 0; mt < 4; ++mt) {
      int m  = mt * 16 + m16;
      int c  = kit * 4 + q;
      int cs = c ^ (m & 7);
      afrag[mt] = *(const short8*)(h_s + (m * 32 + cs) * 8);
    }
    short8 bfrag[4];
    #pragma unroll
    for (int nt = 0; nt < 4; ++nt) {
      int e = e_base + nt * 16 + m16;
      bfrag[nt] = *(const short8*)(w2bf + e * 256 + kit * 32 + q * 8);
    }
    #pragma unroll
    for (int mt = 0; mt < 4; ++mt)
      #pragma unroll
      for (int nt = 0; nt < 4; ++nt)
        acc[mt][nt] = __builtin_amdgcn_mfma_f32_16x16x32_bf16(
            afrag[mt], bfrag[nt], acc[mt][nt], 0, 0, 0);
  }

  // epilogue: + gene_emb[g][e] + b2[e], zero for padding slots
  float b2v[4];
  #pragma unroll
  for (int nt = 0; nt < 4; ++nt) b2v[nt] = b2[e_base + nt * 16 + m16];

  #pragma unroll
  for (int mt = 0; mt < 4; ++mt) {
    #pragma unroll
    for (int r = 0; r < 4; ++r) {
      int mloc = mt * 16 + q * 4 + r;          // C/D row = quad*4+reg
      int slot = slot0 + mloc;
      int g    = s_g[mloc];
      int bb   = slot >> 11;                    // / 2048
      int k    = slot & 2047;
      size_t obase = (size_t)bb * ((Kk + 1) * Dd) + (size_t)(k + 1) * Dd;
      #pragma unroll
      for (int nt = 0; nt < 4; ++nt) {
        int e = e_base + nt * 16 + m16;         // C/D col = lane&15
        float val = 0.0f;
        if (g >= 0)
          val = acc[mt][nt][r] + gene_emb[(size_t)g * Dd + e] + b2v[nt];
        out[obase + e] = val;
      }
    }
  }
}

extern "C" void kernel_launch(void* const* d_in, const int* in_sizes, int n_in,
                              void* d_out, int out_size, void* d_ws, size_t ws_size,
                              hipStream_t stream)
{
  const float* expr     = (const float*)d_in[0];
  const float* gene_emb = (const float*)d_in[1];
  const float* w1       = (const float*)d_in[2];
  const float* b1       = (const float*)d_in[3];
  const float* w2       = (const float*)d_in[4];
  const float* b2       = (const float*)d_in[5];
  const float* cls      = (const float*)d_in[6];
  float* out = (float*)d_out;

  unsigned short* w2bf  = (unsigned short*)d_ws;                       // 131072 B
  int*   comp_idx       = (int*)((char*)d_ws + 131072);                // 131072 B
  float* expr_sel       = (float*)((char*)d_ws + 131072 + Bsz*Kk*4);   // 131072 B

  hipLaunchKernelGGL(k_w2bf,   dim3(64),  dim3(256),  0, stream, w2, w2bf);
  hipLaunchKernelGGL(k_select, dim3(Bsz), dim3(1024), 0, stream, expr, cls,
                     comp_idx, expr_sel, out);
  hipLaunchKernelGGL(k_tokens, dim3((Bsz * Kk) / 64), dim3(256), 0, stream,
                     comp_idx, expr_sel, w1, b1, w2bf, b2, gene_emb, out);
}

// Round 2
// 174.622 us; speedup vs baseline: 1.0942x; 1.0942x over previous
//
#include <hip/hip_runtime.h>
#include <math.h>

#define Bsz 16
#define Gg  20000
#define Dd  256
#define Kk  2048
#define NBIN 16384
#define CAND_CAP 4096

typedef short short8 __attribute__((ext_vector_type(8)));
typedef float f32x4  __attribute__((ext_vector_type(4)));

__device__ __forceinline__ unsigned short f2bf(float f) {
  unsigned u = __float_as_uint(f);
  unsigned r = u + 0x7FFFu + ((u >> 16) & 1u);   // round-to-nearest-even
  return (unsigned short)(r >> 16);
}

__device__ __forceinline__ float gelu_exact(float x) {
  return 0.5f * x * (1.0f + erff(x * 0.70710678118654752f));
}

// ---------------- kernel 1: w2 fp32 -> bf16 ----------------
__global__ __launch_bounds__(256) void k_w2bf(const float* __restrict__ w2,
                                              unsigned short* __restrict__ w2bf) {
  int i = (blockIdx.x * 256 + threadIdx.x) * 4;
  float4 v = *(const float4*)(w2 + i);
  ushort4 o;
  o.x = f2bf(v.x); o.y = f2bf(v.y); o.z = f2bf(v.z); o.w = f2bf(v.w);
  *(ushort4*)(w2bf + i) = o;
}

// ---------------- kernel 2a: 14-bit-key histogram (global atomics) ----------------
// grid (16 rows, 10 slices) x 256 thr; key = bits>>17 spreads [0.5,1) over 64 bins
__global__ __launch_bounds__(256) void k_hist(const float* __restrict__ expr,
                                              unsigned* __restrict__ hist) {
  const int row = blockIdx.x;
  const int i0  = blockIdx.y * 2000;
  const int i1  = (i0 + 2000 < Gg) ? i0 + 2000 : Gg;
  const float* rowp = expr + (size_t)row * Gg;
  unsigned* h = hist + row * NBIN;
  for (int i = i0 + threadIdx.x; i < i1; i += 256) {
    unsigned bits = __float_as_uint(rowp[i]);
    atomicAdd(&h[bits >> 17], 1u);
  }
}

// hierarchical exclusive scan over 1024 threads (16 waves), ~3 barriers
__device__ __forceinline__ unsigned block_scan_excl(unsigned v, unsigned* s_ws,
                                                    unsigned* total) {
  const int lane = threadIdx.x & 63, wid = threadIdx.x >> 6;
  __syncthreads();                       // protect s_ws reuse across calls
  unsigned incl = v;
  #pragma unroll
  for (int off = 1; off < 64; off <<= 1) {
    unsigned u = (unsigned)__shfl_up((int)incl, off);
    if (lane >= off) incl += u;
  }
  if (lane == 63) s_ws[wid] = incl;
  __syncthreads();
  if (wid == 0) {
    unsigned w = (lane < 16) ? s_ws[lane] : 0u;
    unsigned wi = w;
    #pragma unroll
    for (int off = 1; off < 16; off <<= 1) {
      unsigned u = (unsigned)__shfl_up((int)wi, off);
      if (lane >= off) wi += u;
    }
    if (lane < 16) s_ws[lane] = wi - w;  // exclusive wave base
    if (lane == 15) s_ws[16] = wi;       // grand total
  }
  __syncthreads();
  *total = s_ws[16];
  return s_ws[wid] + incl - v;
}

// ---------------- kernel 2b: find exact threshold + compact ----------------
// one block per batch row, 1024 threads
__global__ __launch_bounds__(1024) void k_select2(
    const float* __restrict__ expr, const unsigned* __restrict__ hist,
    const float* __restrict__ cls,
    int* __restrict__ comp_idx, float* __restrict__ expr_sel,
    float* __restrict__ out)
{
  const int b = blockIdx.x, tid = threadIdx.x;
  const float* row = expr + (size_t)b * Gg;
  const unsigned* h = hist + b * NBIN;

  __shared__ unsigned s_ws[17];
  __shared__ unsigned s_cand[CAND_CAP];
  __shared__ unsigned s_B, s_needbin, s_cnt, s_T, s_needeq;

  if (tid == 0) s_cnt = 0u;

  // ---- phase A: find the 14-bit bin containing the K-th largest ----
  const int keytop = NBIN - 1 - tid * 16;     // thread covers 16 descending keys
  unsigned partial = 0;
  #pragma unroll
  for (int i = 0; i < 16; ++i) partial += h[keytop - i];
  unsigned dummy;
  unsigned excl = block_scan_excl(partial, s_ws, &dummy);  // count of keys above chunk
  if (excl < Kk && Kk <= excl + partial) {
    unsigned cum = excl;
    for (int i = 0; i < 16; ++i) {
      unsigned c = h[keytop - i];
      if (cum + c >= Kk) { s_B = (unsigned)(keytop - i); s_needbin = Kk - cum; break; }
      cum += c;
    }
  }
  __syncthreads();
  const unsigned B = s_B, needbin = s_needbin;

  // ---- phase B: collect candidates with key == B ----
  for (int i = tid; i < Gg; i += 1024) {
    unsigned bits = __float_as_uint(row[i]);
    if ((bits >> 17) == B) {
      unsigned p = atomicAdd(&s_cnt, 1u);
      if (p < CAND_CAP) s_cand[p] = bits;
    }
  }
  __syncthreads();
  const unsigned n = (s_cnt < CAND_CAP) ? s_cnt : CAND_CAP;

  // ---- phase C: exact 32-bit threshold among candidates (tie-aware) ----
  for (unsigned i = tid; i < n; i += 1024) {
    unsigned v = s_cand[i];
    unsigned rank = 0, eq = 0;
    for (unsigned j = 0; j < n; ++j) {
      unsigned u = s_cand[j];
      rank += (u > v) ? 1u : 0u;
      eq   += (u == v) ? 1u : 0u;
    }
    if (rank < needbin && needbin <= rank + eq) {
      s_T = v; s_needeq = needbin - rank;     // benign race: same values
    }
  }
  __syncthreads();
  const unsigned T = s_T, need_eq = s_needeq;

  // ---- phase D: stream compaction (contiguous slices keep ascending order) ----
  const int g0 = (tid * 20 < Gg) ? tid * 20 : Gg;
  const int g1 = (g0 + 20 < Gg) ? g0 + 20 : Gg;

  unsigned cnteq = 0;
  for (int g = g0; g < g1; ++g)
    if (__float_as_uint(row[g]) == T) ++cnteq;
  unsigned tot_eq;
  const unsigned excl_eq = block_scan_excl(cnteq, s_ws, &tot_eq);

  unsigned cnt = 0;
  {
    unsigned eqr = excl_eq;
    for (int g = g0; g < g1; ++g) {
      float v = row[g];
      unsigned bits = __float_as_uint(v);
      bool sel;
      if (bits > T)       sel = true;
      else if (bits == T) { sel = (eqr < need_eq); ++eqr; }
      else                sel = false;
      if (sel && v > 0.0f) ++cnt;
    }
  }
  unsigned n_b;
  unsigned pos = block_scan_excl(cnt, s_ws, &n_b);

  {
    unsigned eqr = excl_eq;
    for (int g = g0; g < g1; ++g) {
      float v = row[g];
      unsigned bits = __float_as_uint(v);
      bool sel;
      if (bits > T)       sel = true;
      else if (bits == T) { sel = (eqr < need_eq); ++eqr; }
      else                sel = false;
      if (sel && v > 0.0f) {
        comp_idx[b * Kk + pos] = g;
        expr_sel[b * Kk + pos] = v;
        ++pos;
      }
    }
  }
  for (int k = (int)n_b + tid; k < Kk; k += 1024) {
    comp_idx[b * Kk + k] = -1;
    expr_sel[b * Kk + k] = 0.0f;
  }

  // cls token + mask
  float* tok = out + (size_t)b * (Kk + 1) * Dd;
  if (tid < Dd) tok[tid] = cls[tid];
  float* maskp = out + (size_t)Bsz * (Kk + 1) * Dd + (size_t)b * (Kk + 1);
  for (int i = tid; i <= Kk; i += 1024)
    maskp[i] = (i == 0) ? 1.0f : (((unsigned)(i - 1) < n_b) ? 1.0f : 0.0f);
}

// ---------------- kernel 3: token compute (fused gelu + bf16 MFMA GEMM) ----------------
// block = 256 thr (4 waves), 64 token slots x 256 out dims; wave w owns e in [w*64, w*64+64)
#define TSTRIDE 68   // fp32 row stride in epilogue tile: %4==0 (16B align), mild 4-way read conflict
__global__ __launch_bounds__(256) void k_tokens(
    const int* __restrict__ comp_idx, const float* __restrict__ expr_sel,
    const float* __restrict__ w1, const float* __restrict__ b1,
    const unsigned short* __restrict__ w2bf, const float* __restrict__ b2,
    const float* __restrict__ gene_emb, float* __restrict__ out)
{
  union SM {
    unsigned short h[64 * 256];          // bf16 h-tile, XOR-swizzled 16B chunks
    float t[4 * 32 * TSTRIDE];           // fp32 epilogue tiles (per-wave 32x68)
  };
  __shared__ __align__(16) SM sm;
  __shared__ int   s_g[64];
  __shared__ float s_x[64];

  const int tid   = threadIdx.x;
  const int slot0 = blockIdx.x * 64;

  if (tid < 64) {
    int slot = slot0 + tid;
    int gi = comp_idx[slot];
    s_g[tid] = gi;
    s_x[tid] = (gi >= 0) ? expr_sel[slot] : 0.0f;
  }
  __syncthreads();

  // phase 1: h[m][d] = gelu(x_m * w1[d] + b1[d]) -> bf16 in LDS
  #pragma unroll
  for (int i = 0; i < 8; ++i) {
    int id = tid + 256 * i;
    int m  = id >> 5;
    int c  = id & 31;
    int d0 = c * 8;
    float x = s_x[m];
    float wv[8], bv[8];
    *(float4*)(&wv[0]) = *(const float4*)(w1 + d0);
    *(float4*)(&wv[4]) = *(const float4*)(w1 + d0 + 4);
    *(float4*)(&bv[0]) = *(const float4*)(b1 + d0);
    *(float4*)(&bv[4]) = *(const float4*)(b1 + d0 + 4);
    short8 p;
    #pragma unroll
    for (int j = 0; j < 8; ++j)
      p[j] = (short)f2bf(gelu_exact(x * wv[j] + bv[j]));
    int cs = c ^ (m & 7);
    *(short8*)(sm.h + (m * 32 + cs) * 8) = p;
  }
  __syncthreads();

  // phase 2: GEMM. out[m][e] = sum_d h[m][d] * w2[e][d]
  const int wave = tid >> 6;
  const int lane = tid & 63;
  const int m16  = lane & 15;
  const int q    = lane >> 4;
  const int e_base = wave * 64;

  f32x4 acc[4][4];
  #pragma unroll
  for (int a = 0; a < 4; ++a)
    #pragma unroll
    for (int nn = 0; nn < 4; ++nn)
      acc[a][nn] = (f32x4){0.f, 0.f, 0.f, 0.f};

  #pragma unroll
  for (int kit = 0; kit < 8; ++kit) {
    short8 afrag[4];
    #pragma unroll
    for (int mt = 0; mt < 4; ++mt) {
      int m  = mt * 16 + m16;
      int c  = kit * 4 + q;
      int cs = c ^ (m & 7);
      afrag[mt] = *(const short8*)(sm.h + (m * 32 + cs) * 8);
    }
    short8 bfrag[4];
    #pragma unroll
    for (int nt = 0; nt < 4; ++nt) {
      int e = e_base + nt * 16 + m16;
      bfrag[nt] = *(const short8*)(w2bf + e * 256 + kit * 32 + q * 8);
    }
    #pragma unroll
    for (int mt = 0; mt < 4; ++mt)
      #pragma unroll
      for (int nt = 0; nt < 4; ++nt)
        acc[mt][nt] = __builtin_amdgcn_mfma_f32_16x16x32_bf16(
            afrag[mt], bfrag[nt], acc[mt][nt], 0, 0, 0);
  }
  __syncthreads();   // all a-frag LDS reads done before epilogue overwrites

  // epilogue: LDS transpose -> float4 gather of gene_emb + float4 stores
  float* tw = sm.t + wave * (32 * TSTRIDE);
  const int eh = lane >> 5;              // lane's 32-wide e half-chunk
  const int e0 = e_base + eh * 32;
  float4 b2v[8];
  #pragma unroll
  for (int j = 0; j < 8; ++j) b2v[j] = *(const float4*)(b2 + e0 + j * 4);

  #pragma unroll
  for (int half = 0; half < 2; ++half) {
    #pragma unroll
    for (int mtl = 0; mtl < 2; ++mtl) {
      int mt = half * 2 + mtl;
      #pragma unroll
      for (int nt = 0; nt < 4; ++nt) {
        int e_loc   = nt * 16 + m16;
        int m_basel = mtl * 16 + q * 4;
        #pragma unroll
        for (int r = 0; r < 4; ++r)
          tw[(m_basel + r) * TSTRIDE + e_loc] = acc[mt][nt][r];
      }
    }
    __syncthreads();

    const int m_loc_l = lane & 31;
    const int m_loc   = half * 32 + m_loc_l;
    const int slot    = slot0 + m_loc;
    const int g       = s_g[m_loc];
    const int gs      = (g >= 0) ? g : 0;
    const float* gp   = gene_emb + (size_t)gs * Dd + e0;
    const int bb = slot >> 11, k = slot & 2047;
    float* op = out + (size_t)bb * ((Kk + 1) * Dd) + (size_t)(k + 1) * Dd + e0;
    #pragma unroll
    for (int j = 0; j < 8; ++j) {
      float4 tv = *(float4*)&tw[m_loc_l * TSTRIDE + eh * 32 + j * 4];
      float4 ge = *(const float4*)(gp + j * 4);
      float4 o;
      if (g >= 0) {
        o.x = tv.x + ge.x + b2v[j].x;
        o.y = tv.y + ge.y + b2v[j].y;
        o.z = tv.z + ge.z + b2v[j].z;
        o.w = tv.w + ge.w + b2v[j].w;
      } else {
        o.x = 0.f; o.y = 0.f; o.z = 0.f; o.w = 0.f;
      }
      *(float4*)(op + j * 4) = o;
    }
    __syncthreads();   // before next half overwrites tw
  }
}

extern "C" void kernel_launch(void* const* d_in, const int* in_sizes, int n_in,
                              void* d_out, int out_size, void* d_ws, size_t ws_size,
                              hipStream_t stream)
{
  const float* expr     = (const float*)d_in[0];
  const float* gene_emb = (const float*)d_in[1];
  const float* w1       = (const float*)d_in[2];
  const float* b1       = (const float*)d_in[3];
  const float* w2       = (const float*)d_in[4];
  const float* b2       = (const float*)d_in[5];
  const float* cls      = (const float*)d_in[6];
  float* out = (float*)d_out;

  unsigned short* w2bf = (unsigned short*)d_ws;                        // 128 KB
  int*      comp_idx   = (int*)((char*)d_ws + (128 << 10));            // 128 KB
  float*    expr_sel   = (float*)((char*)d_ws + (256 << 10));          // 128 KB
  unsigned* hist       = (unsigned*)((char*)d_ws + (384 << 10));       // 1 MB

  hipMemsetAsync(hist, 0, Bsz * NBIN * sizeof(unsigned), stream);
  hipLaunchKernelGGL(k_w2bf,    dim3(64),        dim3(256),  0, stream, w2, w2bf);
  hipLaunchKernelGGL(k_hist,    dim3(Bsz, 10),   dim3(256),  0, stream, expr, hist);
  hipLaunchKernelGGL(k_select2, dim3(Bsz),       dim3(1024), 0, stream, expr, hist, cls,
                     comp_idx, expr_sel, out);
  hipLaunchKernelGGL(k_tokens,  dim3((Bsz * Kk) / 64), dim3(256), 0, stream,
                     comp_idx, expr_sel, w1, b1, w2bf, b2, gene_emb, out);
}